// Round 3
// baseline (440.791 us; speedup 1.0000x reference)
//
#include <hip/hip_runtime.h>

#define N_NODES 100000
#define N_EDGES 3200000
#define D_NODE 128
#define D_EDGE 16

#define NPART 8                        // one partial copy per XCD (MI355X has 8)

// ---- ws layout (float units) ----
#define WS_X      0                    // 100000 floats: compacted nodes[:,0]
#define WS_PART   102400               // NPART * N_NODES floats of atomic partials
#define WS_TOTAL  (WS_PART + NPART * N_NODES)

#define E_THREADS 256
#define E_EPT     4                    // edges per thread; 3.2M = 3125*256*4 exactly

// clang-native vectors: __builtin_nontemporal_load requires these (HIP's
// int4/float4 are classes and are rejected — round-2 compile failure).
typedef int   iv4 __attribute__((ext_vector_type(4)));
typedef float fv4 __attribute__((ext_vector_type(4)));

// ---------------------------------------------------------------------------
// K0: zero the per-XCD partials AND compact the node column so the edge pass
// gathers from a 400 KB L2-resident array instead of 512B-strided nodes.
// ---------------------------------------------------------------------------
__global__ void v2_init(const float* __restrict__ nodes,
                        float* __restrict__ x,
                        float* __restrict__ part) {
    int i = blockIdx.x * blockDim.x + threadIdx.x;
    if (i < NPART * N_NODES) part[i] = 0.f;
    if (i < N_NODES)         x[i] = nodes[(size_t)i * D_NODE];
}

// ---------------------------------------------------------------------------
// K1 (fused): one pass over edges. msg = we*edges[e,0] + wn*x[senders[e]],
// atomicAdd into a per-XCD partial copy selected by blockIdx&7. The command
// processor dispatches consecutive workgroups round-robin across the 8 XCDs,
// so blockIdx&7 tracks the physical XCD: each copy's 400 KB stays dirty in
// that XCD's own L2 slice, no cross-XCD line ping-pong. Correctness does NOT
// depend on the mapping (global atomicAdd is device-scope) — only locality.
// Edge-line loads are contiguous 64B lines -> contiguous DRAM bursts;
// nontemporal so the 205 MB stream doesn't evict x / partials from L2.
// ---------------------------------------------------------------------------
__global__ __launch_bounds__(E_THREADS) void v2_edges(
        const float* __restrict__ x,
        const float* __restrict__ edges,
        const int*   __restrict__ senders,
        const int*   __restrict__ receivers,
        const float* __restrict__ w_node,
        const float* __restrict__ w_edge,
        float* __restrict__ part) {
    const float wn = w_node[0];
    const float we = w_edge[0];

    float* p = part + (size_t)(blockIdx.x & (NPART - 1)) * N_NODES;

    const int base = (blockIdx.x * E_THREADS + (int)threadIdx.x) * E_EPT;
    if (base + E_EPT - 1 < N_EDGES) {
        iv4 s = __builtin_nontemporal_load((const iv4*)(senders + base));
        iv4 r = __builtin_nontemporal_load((const iv4*)(receivers + base));
        float e0 = __builtin_nontemporal_load(edges + (size_t)(base + 0) * D_EDGE);
        float e1 = __builtin_nontemporal_load(edges + (size_t)(base + 1) * D_EDGE);
        float e2 = __builtin_nontemporal_load(edges + (size_t)(base + 2) * D_EDGE);
        float e3 = __builtin_nontemporal_load(edges + (size_t)(base + 3) * D_EDGE);
        float x0 = x[s.x], x1 = x[s.y], x2 = x[s.z], x3 = x[s.w];
        atomicAdd(&p[r.x], we * e0 + wn * x0);
        atomicAdd(&p[r.y], we * e1 + wn * x1);
        atomicAdd(&p[r.z], we * e2 + wn * x2);
        atomicAdd(&p[r.w], we * e3 + wn * x3);
    } else {
        for (int e = base; e < N_EDGES; ++e) {
            float ev = edges[(size_t)e * D_EDGE];
            atomicAdd(&p[receivers[e]], we * ev + wn * x[senders[e]]);
        }
    }
}

// ---------------------------------------------------------------------------
// K2: out[i] = wn*x[i] + b + sum over the 8 partial copies. 3.6 MB read.
// ---------------------------------------------------------------------------
__global__ void v2_out(const float* __restrict__ x,
                       const float* __restrict__ part,
                       const float* __restrict__ w_node,
                       const float* __restrict__ b_node,
                       float* __restrict__ out) {
    int i = blockIdx.x * blockDim.x + threadIdx.x;
    if (i >= N_NODES) return;
    float s = w_node[0] * x[i] + b_node[0];
#pragma unroll
    for (int c = 0; c < NPART; ++c) s += part[(size_t)c * N_NODES + i];
    out[i] = s;
}

// ---------------------------------------------------------------------------
// Fallback (workspace too small): direct atomic path into out.
// ---------------------------------------------------------------------------
__global__ void tmp_init_out(const float* __restrict__ nodes,
                             const float* __restrict__ w_node,
                             const float* __restrict__ b_node,
                             float* __restrict__ out) {
    int i = blockIdx.x * blockDim.x + threadIdx.x;
    if (i < N_NODES) out[i] = w_node[0] * nodes[(size_t)i * D_NODE] + b_node[0];
}

__global__ void tmp_edge_scatter_direct(const float* __restrict__ nodes,
                                        const float* __restrict__ edges,
                                        const int*   __restrict__ senders,
                                        const int*   __restrict__ receivers,
                                        const float* __restrict__ w_node,
                                        const float* __restrict__ w_edge,
                                        float* __restrict__ out) {
    const float wn = w_node[0];
    const float we = w_edge[0];
    int base = (blockIdx.x * blockDim.x + threadIdx.x) * 4;
    if (base + 3 < N_EDGES) {
        iv4 s = *(const iv4*)(senders + base);
        iv4 r = *(const iv4*)(receivers + base);
        atomicAdd(&out[r.x], we * edges[(size_t)(base + 0) * D_EDGE] + wn * nodes[(size_t)s.x * D_NODE]);
        atomicAdd(&out[r.y], we * edges[(size_t)(base + 1) * D_EDGE] + wn * nodes[(size_t)s.y * D_NODE]);
        atomicAdd(&out[r.z], we * edges[(size_t)(base + 2) * D_EDGE] + wn * nodes[(size_t)s.z * D_NODE]);
        atomicAdd(&out[r.w], we * edges[(size_t)(base + 3) * D_EDGE] + wn * nodes[(size_t)s.w * D_NODE]);
    } else {
        for (int e = base; e < N_EDGES; ++e) {
            atomicAdd(&out[receivers[e]],
                      we * edges[(size_t)e * D_EDGE] + wn * nodes[(size_t)senders[e] * D_NODE]);
        }
    }
}

extern "C" void kernel_launch(void* const* d_in, const int* in_sizes, int n_in,
                              void* d_out, int out_size, void* d_ws, size_t ws_size,
                              hipStream_t stream) {
    const float* nodes     = (const float*)d_in[0];
    const float* edges     = (const float*)d_in[1];
    const int*   senders   = (const int*)d_in[2];
    const int*   receivers = (const int*)d_in[3];
    const float* w_node    = (const float*)d_in[4];
    const float* w_edge    = (const float*)d_in[5];
    const float* b_node    = (const float*)d_in[6];
    float* out = (float*)d_out;
    float* ws  = (float*)d_ws;

    if (ws_size >= (size_t)WS_TOTAL * sizeof(float)) {
        float* x    = ws + WS_X;
        float* part = ws + WS_PART;

        int threads = 256;
        int init_n  = NPART * N_NODES;           // 800000 covers both zeroing and x
        v2_init<<<(init_n + threads - 1) / threads, threads, 0, stream>>>(
            nodes, x, part);

        int e_blocks = N_EDGES / (E_THREADS * E_EPT);          // 3125 exactly
        v2_edges<<<e_blocks, E_THREADS, 0, stream>>>(
            x, edges, senders, receivers, w_node, w_edge, part);

        v2_out<<<(N_NODES + threads - 1) / threads, threads, 0, stream>>>(
            x, part, w_node, b_node, out);
    } else {
        int threads = 256;
        tmp_init_out<<<(N_NODES + threads - 1) / threads, threads, 0, stream>>>(
            nodes, w_node, b_node, out);
        int n_thr = N_EDGES / 4;
        tmp_edge_scatter_direct<<<(n_thr + threads - 1) / threads, threads, 0, stream>>>(
            nodes, edges, senders, receivers, w_node, w_edge, out);
    }
}

// Round 4
// 438.395 us; speedup vs baseline: 1.0055x; 1.0055x over previous
//
#include <hip/hip_runtime.h>

#define N_NODES 100000
#define N_EDGES 3200000
#define D_NODE 128
#define D_EDGE 16

#define NPART 8                        // one partial copy per XCD (MI355X has 8)

// ---- ws layout (float units) ----
#define WS_X      0                    // 100000 floats: compacted nodes[:,0]
#define WS_PART   102400               // NPART * N_NODES floats of partials
#define WS_TOTAL  (WS_PART + NPART * N_NODES)

#define E_THREADS 256
#define E_EPT     4                    // edges per thread; 3.2M = 3125*256*4 exactly

// clang-native vectors: __builtin_nontemporal_load requires these (HIP's
// int4/float4 are classes and are rejected by the builtin).
typedef int   iv4 __attribute__((ext_vector_type(4)));
typedef float fv4 __attribute__((ext_vector_type(4)));

// Physical XCD id of the CU this wave runs on. HW-verified on MI355X
// (learn_hip m09: s_getreg(HW_REG_XCC_ID) returns 0..7). All waves of a
// workgroup share one CU -> one XCD, so this is workgroup-uniform.
__device__ __forceinline__ unsigned xcd_id() {
    unsigned x;
    asm volatile("s_getreg_b32 %0, hwreg(HW_REG_XCC_ID)" : "=s"(x));
    return x & (NPART - 1);
}

// ---------------------------------------------------------------------------
// K0: zero the per-XCD partials AND compact the node column so the edge pass
// gathers from a 400 KB L2-resident array instead of 512B-strided nodes.
// ---------------------------------------------------------------------------
__global__ void v2_init(const float* __restrict__ nodes,
                        float* __restrict__ x,
                        float* __restrict__ part) {
    int i = blockIdx.x * blockDim.x + threadIdx.x;
    if (i < NPART * N_NODES) part[i] = 0.f;
    if (i < N_NODES)         x[i] = nodes[(size_t)i * D_NODE];
}

// ---------------------------------------------------------------------------
// K1 (fused): one pass over edges. msg = we*edges[e,0] + wn*x[senders[e]],
// accumulated into THIS XCD's partial copy with a WORKGROUP-SCOPE atomic.
//
// Why workgroup scope: round-3 counters showed device-scope atomicAdd pushes
// every RMW past L2 (WRITE_SIZE == 3.2M x 32B, 18.6 G atomics/s ceiling,
// 172 us). Workgroup scope emits global_atomic_add_f32 without the
// device-coherent bit -> the RMW executes in the local XCD's L2.
// Correctness: the copy index is the REAL XCD id (xcd_id()), so all writers
// of a copy share that L2 (their coherence point); the kernel-end release
// writes L2 back, making the partials visible to v2_out.
// Edge/index loads are nontemporal so the 205 MB stream doesn't evict the
// 400 KB x array or the 400 KB dirty partials from the 4 MB L2.
// ---------------------------------------------------------------------------
__global__ __launch_bounds__(E_THREADS) void v2_edges(
        const float* __restrict__ x,
        const float* __restrict__ edges,
        const int*   __restrict__ senders,
        const int*   __restrict__ receivers,
        const float* __restrict__ w_node,
        const float* __restrict__ w_edge,
        float* __restrict__ part) {
    const float wn = w_node[0];
    const float we = w_edge[0];

    float* p = part + (size_t)xcd_id() * N_NODES;

    const int base = (blockIdx.x * E_THREADS + (int)threadIdx.x) * E_EPT;
    if (base + E_EPT - 1 < N_EDGES) {
        iv4 s = __builtin_nontemporal_load((const iv4*)(senders + base));
        iv4 r = __builtin_nontemporal_load((const iv4*)(receivers + base));
        float e0 = __builtin_nontemporal_load(edges + (size_t)(base + 0) * D_EDGE);
        float e1 = __builtin_nontemporal_load(edges + (size_t)(base + 1) * D_EDGE);
        float e2 = __builtin_nontemporal_load(edges + (size_t)(base + 2) * D_EDGE);
        float e3 = __builtin_nontemporal_load(edges + (size_t)(base + 3) * D_EDGE);
        float m0 = we * e0 + wn * x[s.x];
        float m1 = we * e1 + wn * x[s.y];
        float m2 = we * e2 + wn * x[s.z];
        float m3 = we * e3 + wn * x[s.w];
        __hip_atomic_fetch_add(&p[r.x], m0, __ATOMIC_RELAXED, __HIP_MEMORY_SCOPE_WORKGROUP);
        __hip_atomic_fetch_add(&p[r.y], m1, __ATOMIC_RELAXED, __HIP_MEMORY_SCOPE_WORKGROUP);
        __hip_atomic_fetch_add(&p[r.z], m2, __ATOMIC_RELAXED, __HIP_MEMORY_SCOPE_WORKGROUP);
        __hip_atomic_fetch_add(&p[r.w], m3, __ATOMIC_RELAXED, __HIP_MEMORY_SCOPE_WORKGROUP);
    } else {
        for (int e = base; e < N_EDGES; ++e) {
            float ev = edges[(size_t)e * D_EDGE];
            float m  = we * ev + wn * x[senders[e]];
            __hip_atomic_fetch_add(&p[receivers[e]], m, __ATOMIC_RELAXED, __HIP_MEMORY_SCOPE_WORKGROUP);
        }
    }
}

// ---------------------------------------------------------------------------
// K2: out[i] = wn*x[i] + b + sum over the 8 partial copies. 3.6 MB read.
// ---------------------------------------------------------------------------
__global__ void v2_out(const float* __restrict__ x,
                       const float* __restrict__ part,
                       const float* __restrict__ w_node,
                       const float* __restrict__ b_node,
                       float* __restrict__ out) {
    int i = blockIdx.x * blockDim.x + threadIdx.x;
    if (i >= N_NODES) return;
    float s = w_node[0] * x[i] + b_node[0];
#pragma unroll
    for (int c = 0; c < NPART; ++c) s += part[(size_t)c * N_NODES + i];
    out[i] = s;
}

// ---------------------------------------------------------------------------
// Fallback (workspace too small): direct device-scope atomic path into out.
// ---------------------------------------------------------------------------
__global__ void tmp_init_out(const float* __restrict__ nodes,
                             const float* __restrict__ w_node,
                             const float* __restrict__ b_node,
                             float* __restrict__ out) {
    int i = blockIdx.x * blockDim.x + threadIdx.x;
    if (i < N_NODES) out[i] = w_node[0] * nodes[(size_t)i * D_NODE] + b_node[0];
}

__global__ void tmp_edge_scatter_direct(const float* __restrict__ nodes,
                                        const float* __restrict__ edges,
                                        const int*   __restrict__ senders,
                                        const int*   __restrict__ receivers,
                                        const float* __restrict__ w_node,
                                        const float* __restrict__ w_edge,
                                        float* __restrict__ out) {
    const float wn = w_node[0];
    const float we = w_edge[0];
    int base = (blockIdx.x * blockDim.x + threadIdx.x) * 4;
    if (base + 3 < N_EDGES) {
        iv4 s = *(const iv4*)(senders + base);
        iv4 r = *(const iv4*)(receivers + base);
        atomicAdd(&out[r.x], we * edges[(size_t)(base + 0) * D_EDGE] + wn * nodes[(size_t)s.x * D_NODE]);
        atomicAdd(&out[r.y], we * edges[(size_t)(base + 1) * D_EDGE] + wn * nodes[(size_t)s.y * D_NODE]);
        atomicAdd(&out[r.z], we * edges[(size_t)(base + 2) * D_EDGE] + wn * nodes[(size_t)s.z * D_NODE]);
        atomicAdd(&out[r.w], we * edges[(size_t)(base + 3) * D_EDGE] + wn * nodes[(size_t)s.w * D_NODE]);
    } else {
        for (int e = base; e < N_EDGES; ++e) {
            atomicAdd(&out[receivers[e]],
                      we * edges[(size_t)e * D_EDGE] + wn * nodes[(size_t)senders[e] * D_NODE]);
        }
    }
}

extern "C" void kernel_launch(void* const* d_in, const int* in_sizes, int n_in,
                              void* d_out, int out_size, void* d_ws, size_t ws_size,
                              hipStream_t stream) {
    const float* nodes     = (const float*)d_in[0];
    const float* edges     = (const float*)d_in[1];
    const int*   senders   = (const int*)d_in[2];
    const int*   receivers = (const int*)d_in[3];
    const float* w_node    = (const float*)d_in[4];
    const float* w_edge    = (const float*)d_in[5];
    const float* b_node    = (const float*)d_in[6];
    float* out = (float*)d_out;
    float* ws  = (float*)d_ws;

    if (ws_size >= (size_t)WS_TOTAL * sizeof(float)) {
        float* x    = ws + WS_X;
        float* part = ws + WS_PART;

        int threads = 256;
        int init_n  = NPART * N_NODES;           // 800000 covers both zeroing and x
        v2_init<<<(init_n + threads - 1) / threads, threads, 0, stream>>>(
            nodes, x, part);

        int e_blocks = N_EDGES / (E_THREADS * E_EPT);          // 3125 exactly
        v2_edges<<<e_blocks, E_THREADS, 0, stream>>>(
            x, edges, senders, receivers, w_node, w_edge, part);

        v2_out<<<(N_NODES + threads - 1) / threads, threads, 0, stream>>>(
            x, part, w_node, b_node, out);
    } else {
        int threads = 256;
        tmp_init_out<<<(N_NODES + threads - 1) / threads, threads, 0, stream>>>(
            nodes, w_node, b_node, out);
        int n_thr = N_EDGES / 4;
        tmp_edge_scatter_direct<<<(n_thr + threads - 1) / threads, threads, 0, stream>>>(
            nodes, edges, senders, receivers, w_node, w_edge, out);
    }
}

// Round 5
// 367.203 us; speedup vs baseline: 1.2004x; 1.1939x over previous
//
#include <hip/hip_runtime.h>

#define N_NODES 100000
#define N_EDGES 3200000
#define D_NODE 128
#define D_EDGE 16

#define NR 7                 // node ranges == buckets; SPAN*NR >= N_NODES
#define SPAN 16384           // pow2: bucket = r>>14, local = r & 16383; 64KB fp32 LDS
#define CAP 560000           // per-bucket capacity (expected 524288 +- ~700)
#define NSLICE 64            // K2 slices per range -> 448 blocks, partials 25.6MB

#define K1_THREADS 512
#define K1_EDGES 1024        // edges per K1 block; 3.2M/1024 = 3125 blocks exact

// ---- ws layout (float units) ----
#define WS_X     0                         // 100000: compacted nodes[:,0]
#define WS_CNT   100000                    // 8 ints: bucket counters
#define WS_OVF   100008                    // 100000: overflow accumulator (never hit in practice)
#define WS_BKT   200008                    // NR*CAP*2 floats of (local,msg) pairs; 8B-aligned
#define WS_PART  (WS_BKT + NR * CAP * 2)   // 8040008: NSLICE rows x N_NODES partials
#define WS_TOTAL (WS_PART + NSLICE * N_NODES)   // 14440008 floats ~= 57.8 MB

// clang-native vectors (__builtin_nontemporal_load rejects HIP's class-type int4)
typedef int   iv2 __attribute__((ext_vector_type(2)));
typedef int   iv4 __attribute__((ext_vector_type(4)));
typedef float fv4 __attribute__((ext_vector_type(4)));

// ---------------------------------------------------------------------------
// K0: zero counters + overflow acc, compact node column (x gathers then hit
// a 400 KB cache-resident array instead of 512B-strided nodes).
// ---------------------------------------------------------------------------
__global__ void v3_init(const float* __restrict__ nodes,
                        float* __restrict__ x,
                        float* __restrict__ ovf,
                        int*   __restrict__ cnt) {
    int i = blockIdx.x * blockDim.x + threadIdx.x;
    if (i < 8) cnt[i] = 0;
    if (i < N_NODES) {
        x[i]   = nodes[(size_t)i * D_NODE];
        ovf[i] = 0.f;
    }
}

// ---------------------------------------------------------------------------
// K1: compute msg = we*edges[e,0] + wn*x[senders[e]] and partition
// (local_node, msg) into NR range-buckets. Block-level LDS staging means the
// global bucket counters take ONE atomic per bucket per block (3125*7=21.9K
// device atomics total, vs 3.2M in rounds 3/4 which proved memory-side RMW
// at ~18.7G/s is the wall). Copy-out writes contiguous per-bucket segments.
// ---------------------------------------------------------------------------
__global__ __launch_bounds__(K1_THREADS) void v3_bucketize(
        const float* __restrict__ x,
        const float* __restrict__ edges,
        const int*   __restrict__ senders,
        const int*   __restrict__ receivers,
        const float* __restrict__ w_node,
        const float* __restrict__ w_edge,
        int*   __restrict__ cnt,
        float* __restrict__ ovf,
        int*   __restrict__ bkt) {
    __shared__ int   s_loc[NR * K1_EDGES];       // 28 KB
    __shared__ float s_msg[NR * K1_EDGES];       // 28 KB
    __shared__ int   s_lcnt[NR], s_gbase[NR], s_offs[NR + 1];

    const float wn = w_node[0];
    const float we = w_edge[0];
    const int tile = blockIdx.x * K1_EDGES;      // 3125*1024 == N_EDGES exactly

    if (threadIdx.x < NR) s_lcnt[threadIdx.x] = 0;
    __syncthreads();

    // one memory round for both sub-iterations (loads issued before staging)
    int rr[2]; float mm[2];
#pragma unroll
    for (int j = 0; j < 2; ++j) {
        int e = tile + j * K1_THREADS + (int)threadIdx.x;
        rr[j]    = __builtin_nontemporal_load(receivers + e);
        int s    = __builtin_nontemporal_load(senders + e);
        float ev = __builtin_nontemporal_load(edges + (size_t)e * D_EDGE);
        mm[j] = we * ev + wn * x[s];
    }
#pragma unroll
    for (int j = 0; j < 2; ++j) {
        int b   = rr[j] >> 14;                   // SPAN = 2^14
        int pos = atomicAdd(&s_lcnt[b], 1);      // LDS atomic, cheap
        s_loc[b * K1_EDGES + pos] = rr[j] & (SPAN - 1);
        s_msg[b * K1_EDGES + pos] = mm[j];
    }
    __syncthreads();

    if (threadIdx.x < NR)
        s_gbase[threadIdx.x] = atomicAdd(&cnt[threadIdx.x], s_lcnt[threadIdx.x]);
    if (threadIdx.x == 0) {
        int o = 0;
        for (int b = 0; b < NR; ++b) { s_offs[b] = o; o += s_lcnt[b]; }
        s_offs[NR] = o;                          // == K1_EDGES
    }
    __syncthreads();

    const int tot = s_offs[NR];
    for (int i = threadIdx.x; i < tot; i += K1_THREADS) {
        int b = 0;
        while (i >= s_offs[b + 1]) ++b;          // <=7 compares
        int k   = i - s_offs[b];
        int gi  = s_gbase[b] + k;
        int loc = s_loc[b * K1_EDGES + k];
        float m = s_msg[b * K1_EDGES + k];
        if (gi < CAP) {
            iv2 v; v.x = loc; v.y = __float_as_int(m);
            *(iv2*)(bkt + ((size_t)b * CAP + gi) * 2) = v;
        } else {                                  // statistically never (CAP-expected > 35 sigma)
            atomicAdd(&ovf[b * SPAN + loc], m);
        }
    }
}

// ---------------------------------------------------------------------------
// K2: grid (NSLICE, NR). Block (s, r) reads its contiguous slice of bucket r
// ONCE (no filter, no divergence), LDS-atomicAdds into the 64 KB range
// accumulator, then overwrites its span of partials row s (no pre-zeroing:
// every (s,r) block writes its full span, zeros included).
// ---------------------------------------------------------------------------
__global__ __launch_bounds__(1024) void v3_accum(
        const int* __restrict__ bkt,
        const int* __restrict__ cnt,
        float* __restrict__ partials) {
    extern __shared__ float acc[];               // SPAN floats = 64 KB dynamic
    const int r  = blockIdx.y;
    const int lo = r * SPAN;
    int span = N_NODES - lo; if (span > SPAN) span = SPAN;

    const int n     = cnt[r];
    const int chunk = (n + NSLICE - 1) / NSLICE;
    int start = blockIdx.x * chunk;
    int end   = start + chunk; if (end > n) end = n;

    for (int i = threadIdx.x * 4; i < SPAN; i += 4096) {
        fv4 z = {0.f, 0.f, 0.f, 0.f};
        *(fv4*)(acc + i) = z;
    }
    __syncthreads();

    const int* base = bkt + (size_t)r * CAP * 2;
    for (int i = start + (int)threadIdx.x; i < end; i += 1024) {
        iv2 v = *(const iv2*)(base + (size_t)i * 2);
        atomicAdd(&acc[v.x], __int_as_float(v.y));
    }
    __syncthreads();

    float* dst = partials + (size_t)blockIdx.x * N_NODES + lo;
    for (int i = threadIdx.x * 4; i < span; i += 4096)   // span % 4 == 0 (16384/1696)
        *(fv4*)(dst + i) = *(const fv4*)(acc + i);
}

// ---------------------------------------------------------------------------
// K3: out[i] = wn*x[i] + b + ovf[i] + sum_s partials[s][i].  ~26 MB read.
// ---------------------------------------------------------------------------
__global__ void v3_out(const float* __restrict__ x,
                       const float* __restrict__ partials,
                       const float* __restrict__ ovf,
                       const float* __restrict__ w_node,
                       const float* __restrict__ b_node,
                       float* __restrict__ out) {
    int i = blockIdx.x * blockDim.x + threadIdx.x;
    if (i >= N_NODES) return;
    float s = w_node[0] * x[i] + b_node[0] + ovf[i];
#pragma unroll 8
    for (int c = 0; c < NSLICE; ++c) s += partials[(size_t)c * N_NODES + i];
    out[i] = s;
}

// ---------------------------------------------------------------------------
// Fallback (workspace too small): direct atomic path (known-correct).
// ---------------------------------------------------------------------------
__global__ void tmp_init_out(const float* __restrict__ nodes,
                             const float* __restrict__ w_node,
                             const float* __restrict__ b_node,
                             float* __restrict__ out) {
    int i = blockIdx.x * blockDim.x + threadIdx.x;
    if (i < N_NODES) out[i] = w_node[0] * nodes[(size_t)i * D_NODE] + b_node[0];
}

__global__ void tmp_edge_scatter_direct(const float* __restrict__ nodes,
                                        const float* __restrict__ edges,
                                        const int*   __restrict__ senders,
                                        const int*   __restrict__ receivers,
                                        const float* __restrict__ w_node,
                                        const float* __restrict__ w_edge,
                                        float* __restrict__ out) {
    const float wn = w_node[0];
    const float we = w_edge[0];
    int base = (blockIdx.x * blockDim.x + threadIdx.x) * 4;
    if (base + 3 < N_EDGES) {
        iv4 s = *(const iv4*)(senders + base);
        iv4 r = *(const iv4*)(receivers + base);
        atomicAdd(&out[r.x], we * edges[(size_t)(base + 0) * D_EDGE] + wn * nodes[(size_t)s.x * D_NODE]);
        atomicAdd(&out[r.y], we * edges[(size_t)(base + 1) * D_EDGE] + wn * nodes[(size_t)s.y * D_NODE]);
        atomicAdd(&out[r.z], we * edges[(size_t)(base + 2) * D_EDGE] + wn * nodes[(size_t)s.z * D_NODE]);
        atomicAdd(&out[r.w], we * edges[(size_t)(base + 3) * D_EDGE] + wn * nodes[(size_t)s.w * D_NODE]);
    } else {
        for (int e = base; e < N_EDGES; ++e) {
            atomicAdd(&out[receivers[e]],
                      we * edges[(size_t)e * D_EDGE] + wn * nodes[(size_t)senders[e] * D_NODE]);
        }
    }
}

extern "C" void kernel_launch(void* const* d_in, const int* in_sizes, int n_in,
                              void* d_out, int out_size, void* d_ws, size_t ws_size,
                              hipStream_t stream) {
    const float* nodes     = (const float*)d_in[0];
    const float* edges     = (const float*)d_in[1];
    const int*   senders   = (const int*)d_in[2];
    const int*   receivers = (const int*)d_in[3];
    const float* w_node    = (const float*)d_in[4];
    const float* w_edge    = (const float*)d_in[5];
    const float* b_node    = (const float*)d_in[6];
    float* out = (float*)d_out;
    float* ws  = (float*)d_ws;

    if (ws_size >= (size_t)WS_TOTAL * sizeof(float)) {
        float* x    = ws + WS_X;
        int*   cnt  = (int*)(ws + WS_CNT);
        float* ovf  = ws + WS_OVF;
        int*   bkt  = (int*)(ws + WS_BKT);
        float* part = ws + WS_PART;

        int threads = 256;
        v3_init<<<(N_NODES + threads - 1) / threads, threads, 0, stream>>>(
            nodes, x, ovf, cnt);

        v3_bucketize<<<N_EDGES / K1_EDGES, K1_THREADS, 0, stream>>>(
            x, edges, senders, receivers, w_node, w_edge, cnt, ovf, bkt);

        dim3 grid2(NSLICE, NR);
        v3_accum<<<grid2, 1024, SPAN * sizeof(float), stream>>>(bkt, cnt, part);

        v3_out<<<(N_NODES + threads - 1) / threads, threads, 0, stream>>>(
            x, part, ovf, w_node, b_node, out);
    } else {
        int threads = 256;
        tmp_init_out<<<(N_NODES + threads - 1) / threads, threads, 0, stream>>>(
            nodes, w_node, b_node, out);
        int n_thr = N_EDGES / 4;
        tmp_edge_scatter_direct<<<(n_thr + threads - 1) / threads, threads, 0, stream>>>(
            nodes, edges, senders, receivers, w_node, w_edge, out);
    }
}